// Round 6
// baseline (935.579 us; speedup 1.0000x reference)
//
#include <hip/hip_runtime.h>

#define PP   512
#define CC   32
#define HWD  3072           // 64*48
#define PDIMK 34
#define NIMG 32

static constexpr float INV_NORM  = 1.0f / 96.0f;
static constexpr float INV_PNORM = 1.0f / 480.0f;

// workspace int layout:
// [0..32]      gstart (33)
// [33]         npairs
// [64..575]    start[i]
// [576..1087]  cnt[i]
// [1088..1599] pairBase[i]  (exclusive prefix sum of cnt)
// byte 8192+:  rel/att buffer, TRANSPOSED layout [c][strideP] floats

__global__ void k_groups(const int* __restrict__ imgid, int* __restrict__ wsI) {
    __shared__ int s_img[PP];
    __shared__ int s_cnt[PP];
    int t = threadIdx.x;
    s_img[t] = imgid[t];
    __syncthreads();
    int v = s_img[t];
    int lo = 0, hi = PP;
    while (lo < hi) { int mid = (lo + hi) >> 1; if (s_img[mid] < v) lo = mid + 1; else hi = mid; }
    int st = lo;
    lo = 0; hi = PP;
    while (lo < hi) { int mid = (lo + hi) >> 1; if (s_img[mid] <= v) lo = mid + 1; else hi = mid; }
    int cn = lo - st;
    wsI[64 + t]  = st;
    wsI[576 + t] = cn;
    s_cnt[t] = cn;
    if (t <= NIMG) {
        lo = 0; hi = PP;
        while (lo < hi) { int mid = (lo + hi) >> 1; if (s_img[mid] < t) lo = mid + 1; else hi = mid; }
        wsI[t] = lo;
    }
    __syncthreads();
    if (t == 0) {
        int acc = 0;
        for (int i = 0; i < PP; ++i) { wsI[1088 + i] = acc; acc += s_cnt[i]; }
        wsI[33] = acc;
    }
}

// rel[c][p(i,j)] = dot(x[c,i,:], x[c,j,:]) / 96   (transposed layout)
// Column-parallel: lane = 4 columns, wave = 4x4 pair sub-tile (16 scalar accs
// -> no spill), 4-wave block covers an 8x8 pair tile. 8x8 tiles over (i,j)
// distributed across blockIdx.z. One LDS-transpose reduce per tile.
__global__ __launch_bounds__(256) void k_rel(const float* __restrict__ feats,
                                             const int* __restrict__ wsI,
                                             float* __restrict__ relbuf, int strideP) {
    __shared__ float S[16][260];    // rows 0-7: i-side, 8-15: j-side; 16.6 KB
    int m = blockIdx.x, c = blockIdx.y, z = blockIdx.z;
    int g0 = wsI[m], n = wsI[m + 1] - g0;
    if (n <= 0) return;
    const int* pairBase = wsI + 1088;
    int t = threadIdx.x;
    int wave = t >> 6, lane = t & 63;
    int srow = t >> 4, scol = (t & 15) * 4;        // staging: 16 rows x 64 cols/pass
    int lane4 = lane * 4;                          // compute: col-base (256 cols)
    int wa = 4 * (wave >> 1), wb = 4 * (wave & 1); // wave's 4x4 sub-tile in 8x8
    int nt = (n + 7) >> 3;                         // 8-row tiles

    for (int tile = z; tile < nt * nt; tile += 4) {
        int ti = tile / nt, tj = tile - ti * nt;
        int i0 = 8 * ti, j0 = 8 * tj;

        float acc[4][4];
#pragma unroll
        for (int a = 0; a < 4; ++a)
#pragma unroll
            for (int b = 0; b < 4; ++b) acc[a][b] = 0.f;

        // this thread's one staging row: srow<8 -> i-side, else j-side
        int r = (srow < 8) ? (i0 + srow) : (j0 + srow - 8);
        if (r >= n) r = n - 1;                     // clamp (guarded at write)
        const float* row = feats + ((size_t)(g0 + r) * CC + c) * HWD;

        float4 pf[4];
#pragma unroll
        for (int ps = 0; ps < 4; ++ps) pf[ps] = *(const float4*)&row[scol + 64 * ps];

        for (int d0 = 0; d0 < HWD; d0 += 256) {
            __syncthreads();   // previous compute done reading S
#pragma unroll
            for (int ps = 0; ps < 4; ++ps) *(float4*)&S[srow][scol + 64 * ps] = pf[ps];
            int dn = (d0 + 256 < HWD) ? d0 + 256 : 0;   // prefetch next (wrap harmless)
#pragma unroll
            for (int ps = 0; ps < 4; ++ps) pf[ps] = *(const float4*)&row[dn + scol + 64 * ps];
            __syncthreads();   // staged data ready
            float4 xi[4];
#pragma unroll
            for (int a = 0; a < 4; ++a) xi[a] = *(const float4*)&S[wa + a][lane4];
#pragma unroll
            for (int b = 0; b < 4; ++b) {
                float4 xj = *(const float4*)&S[8 + wb + b][lane4];
#pragma unroll
                for (int a = 0; a < 4; ++a) {
                    acc[a][b] += xi[a].x * xj.x;
                    acc[a][b] += xi[a].y * xj.y;
                    acc[a][b] += xi[a].z * xj.z;
                    acc[a][b] += xi[a].w * xj.w;
                }
            }
        }

        __syncthreads();   // all waves done with S -> reuse as reduce scratch
        float* red = &S[0][0] + wave * 1040;   // per-wave [16][65]
#pragma unroll
        for (int k = 0; k < 16; ++k)
            red[k * 65 + lane] = acc[k >> 2][k & 3];
        float s = 0.f;
#pragma unroll
        for (int k2 = 0; k2 < 16; ++k2)
            s += red[(lane & 15) * 65 + (lane >> 4) * 16 + k2];
        s += __shfl_xor(s, 16);
        s += __shfl_xor(s, 32);
        if (lane < 16) {
            int i = i0 + wa + (lane >> 2);
            int j = j0 + wb + (lane & 3);
            if (i < n && j < n) {
                int p = pairBase[g0 + i] + j;
                if (p < strideP) relbuf[(size_t)c * strideP + p] = s * INV_NORM;
            }
        }
    }
}

// softmax over channels, tiled transpose for coalescing; adds param term
__global__ __launch_bounds__(256) void k_softmax(float* __restrict__ relbuf,
                                                 const float* __restrict__ param,
                                                 const int* __restrict__ wsI, int strideP) {
    int np = wsI[33];
    if (np > strideP) np = strideP;
    int p0 = blockIdx.x * 64;
    if (p0 >= np) return;
    int nv = min(64, np - p0);
    __shared__ float tile[CC][68];   // 8.7 KB
    int t = threadIdx.x;
    for (int idx = t; idx < CC * 16; idx += 256) {
        int c = idx >> 4, q4 = (idx & 15) * 4;
        if (q4 + 4 <= nv) {
            *(float4*)&tile[c][q4] = *(const float4*)&relbuf[(size_t)c * strideP + p0 + q4];
        } else {
#pragma unroll
            for (int e = 0; e < 4; ++e)
                if (q4 + e < nv) tile[c][q4 + e] = relbuf[(size_t)c * strideP + p0 + q4 + e];
        }
    }
    __syncthreads();
    if (t < 64 && t < nv) {
        int p = p0 + t;
        const int* pairBase = wsI + 1088;
        int lo = 0, hi = PP - 1;
        while (lo < hi) { int mid = (lo + hi + 1) >> 1; if (pairBase[mid] <= p) lo = mid; else hi = mid - 1; }
        int i = lo;
        int j = wsI[64 + i] + (p - pairBase[i]);
        float pd = 0.f;
#pragma unroll
        for (int k = 0; k < PDIMK; ++k) pd += param[i * PDIMK + k] * param[j * PDIMK + k];
        pd *= INV_PNORM;
        float mx = -3.4e38f;
#pragma unroll
        for (int c = 0; c < CC; ++c) mx = fmaxf(mx, tile[c][t] + pd);
        float s = 0.f;
#pragma unroll
        for (int c = 0; c < CC; ++c) { float e = __expf(tile[c][t] + pd - mx); tile[c][t] = e; s += e; }
        float inv = 1.0f / s;
#pragma unroll
        for (int c = 0; c < CC; ++c) tile[c][t] *= inv;
    }
    __syncthreads();
    for (int idx = t; idx < CC * 16; idx += 256) {
        int c = idx >> 4, q4 = (idx & 15) * 4;
        if (q4 + 4 <= nv) {
            *(float4*)&relbuf[(size_t)c * strideP + p0 + q4] = *(const float4*)&tile[c][q4];
        } else {
#pragma unroll
            for (int e = 0; e < 4; ++e)
                if (q4 + e < nv) relbuf[(size_t)c * strideP + p0 + q4 + e] = tile[c][q4 + e];
        }
    }
}

// out[i,c,d] = relu( sum_j (att[c,i,j] + delta_ij) * x[j,c,d] )
__global__ __launch_bounds__(256) void k_out(const float* __restrict__ feats,
                                             const float* __restrict__ att,
                                             const int* __restrict__ wsI,
                                             float* __restrict__ out, int strideP) {
    __shared__ float att_t[32][20];    // [jj][ii], 2.5 KB
    int m = blockIdx.x, c = blockIdx.y;
    int g0 = wsI[m], n = wsI[m + 1] - g0;
    if (n <= 0) return;
    const int* pairBase = wsI + 1088;
    int t = threadIdx.x;
    int col = blockIdx.z * 1024 + t * 4;
    const size_t rs = (size_t)CC * HWD;                     // row stride (floats)
    const float* fb = feats + ((size_t)g0 * CC + c) * HWD + col;
    float*       ob = out   + ((size_t)g0 * CC + c) * HWD + col;

    for (int ic = 0; ic < n; ic += 16) {
        int ni = min(16, n - ic);
        float4 acc[16];
#pragma unroll
        for (int q = 0; q < 16; ++q) acc[q] = make_float4(0.f, 0.f, 0.f, 0.f);
        for (int jc = 0; jc < n; jc += 32) {
            int nj = min(32, n - jc);
            __syncthreads();
            for (int idx = t; idx < 512; idx += 256) {      // 32 jj x 16 ii
                int jj = idx & 31, ii = idx >> 5;
                float a = 0.f;
                if (ii < ni && jj < nj) {
                    int p = pairBase[g0 + ic + ii] + jc + jj;
                    if (p < strideP) a = att[(size_t)c * strideP + p];
                    if (ic + ii == jc + jj) a += 1.0f;      // residual folded in
                }
                att_t[jj][ii] = a;
            }
            __syncthreads();
            const float* fj = fb + (size_t)jc * rs;
            float4 vnext = *(const float4*)fj;              // nj >= 1 always here
            for (int jj = 0; jj < nj; ++jj) {
                float4 vj = vnext;
                if (jj + 1 < nj) vnext = *(const float4*)(fj + (size_t)(jj + 1) * rs);
                float4 a0 = *(const float4*)&att_t[jj][0];   // broadcast reads
                float4 a1 = *(const float4*)&att_t[jj][4];
                float4 a2 = *(const float4*)&att_t[jj][8];
                float4 a3 = *(const float4*)&att_t[jj][12];
                acc[0].x  += a0.x * vj.x; acc[0].y  += a0.x * vj.y; acc[0].z  += a0.x * vj.z; acc[0].w  += a0.x * vj.w;
                acc[1].x  += a0.y * vj.x; acc[1].y  += a0.y * vj.y; acc[1].z  += a0.y * vj.z; acc[1].w  += a0.y * vj.w;
                acc[2].x  += a0.z * vj.x; acc[2].y  += a0.z * vj.y; acc[2].z  += a0.z * vj.z; acc[2].w  += a0.z * vj.w;
                acc[3].x  += a0.w * vj.x; acc[3].y  += a0.w * vj.y; acc[3].z  += a0.w * vj.z; acc[3].w  += a0.w * vj.w;
                acc[4].x  += a1.x * vj.x; acc[4].y  += a1.x * vj.y; acc[4].z  += a1.x * vj.z; acc[4].w  += a1.x * vj.w;
                acc[5].x  += a1.y * vj.x; acc[5].y  += a1.y * vj.y; acc[5].z  += a1.y * vj.z; acc[5].w  += a1.y * vj.w;
                acc[6].x  += a1.z * vj.x; acc[6].y  += a1.z * vj.y; acc[6].z  += a1.z * vj.z; acc[6].w  += a1.z * vj.w;
                acc[7].x  += a1.w * vj.x; acc[7].y  += a1.w * vj.y; acc[7].z  += a1.w * vj.z; acc[7].w  += a1.w * vj.w;
                acc[8].x  += a2.x * vj.x; acc[8].y  += a2.x * vj.y; acc[8].z  += a2.x * vj.z; acc[8].w  += a2.x * vj.w;
                acc[9].x  += a2.y * vj.x; acc[9].y  += a2.y * vj.y; acc[9].z  += a2.y * vj.z; acc[9].w  += a2.y * vj.w;
                acc[10].x += a2.z * vj.x; acc[10].y += a2.z * vj.y; acc[10].z += a2.z * vj.z; acc[10].w += a2.z * vj.w;
                acc[11].x += a2.w * vj.x; acc[11].y += a2.w * vj.y; acc[11].z += a2.w * vj.z; acc[11].w += a2.w * vj.w;
                acc[12].x += a3.x * vj.x; acc[12].y += a3.x * vj.y; acc[12].z += a3.x * vj.z; acc[12].w += a3.x * vj.w;
                acc[13].x += a3.y * vj.x; acc[13].y += a3.y * vj.y; acc[13].z += a3.y * vj.z; acc[13].w += a3.y * vj.w;
                acc[14].x += a3.z * vj.x; acc[14].y += a3.z * vj.y; acc[14].z += a3.z * vj.z; acc[14].w += a3.z * vj.w;
                acc[15].x += a3.w * vj.x; acc[15].y += a3.w * vj.y; acc[15].z += a3.w * vj.z; acc[15].w += a3.w * vj.w;
            }
        }
#pragma unroll
        for (int ii = 0; ii < 16; ++ii) {
            if (ii < ni) {
                float4 r = acc[ii];
                r.x = fmaxf(r.x, 0.f); r.y = fmaxf(r.y, 0.f);
                r.z = fmaxf(r.z, 0.f); r.w = fmaxf(r.w, 0.f);
                *(float4*)&ob[(size_t)(ic + ii) * rs] = r;
            }
        }
    }
}

extern "C" void kernel_launch(void* const* d_in, const int* in_sizes, int n_in,
                              void* d_out, int out_size, void* d_ws, size_t ws_size,
                              hipStream_t stream) {
    const float* feats = (const float*)d_in[0];
    const int*   imgid = (const int*)d_in[1];
    const float* param = (const float*)d_in[2];
    float* out = (float*)d_out;
    int* wsI = (int*)d_ws;
    float* relbuf = (float*)((char*)d_ws + 8192);

    long capL = ((long)ws_size - 8192) / (CC * 4);
    if (capL < 0) capL = 0;
    if (capL > (long)PP * PP) capL = (long)PP * PP;
    int strideP = (int)capL;

    k_groups<<<1, PP, 0, stream>>>(imgid, wsI);
    k_rel<<<dim3(NIMG, CC, 4), 256, 0, stream>>>(feats, wsI, relbuf, strideP);
    k_softmax<<<dim3((PP * PP + 63) / 64), 256, 0, stream>>>(relbuf, param, wsI, strideP);
    k_out<<<dim3(NIMG, CC, 3), 256, 0, stream>>>(feats, relbuf, wsI, out, strideP);
}

// Round 7
// 262.212 us; speedup vs baseline: 3.5680x; 3.5680x over previous
//
#include <hip/hip_runtime.h>

#define PP   512
#define CC   32
#define HWD  3072           // 64*48
#define PDIMK 34
#define NIMG 32

static constexpr float INV_NORM  = 1.0f / 96.0f;
static constexpr float INV_PNORM = 1.0f / 480.0f;

typedef short bf16x8 __attribute__((ext_vector_type(8)));
typedef float f32x4  __attribute__((ext_vector_type(4)));

__device__ __forceinline__ short f2bf(float f) {   // RNE fp32 -> bf16 bits
    unsigned u = __float_as_uint(f);
    u += 0x7FFF + ((u >> 16) & 1);
    return (short)(u >> 16);
}

// workspace int layout:
// [0..32]      gstart (33)
// [33]         npairs
// [64..575]    start[i]
// [576..1087]  cnt[i]
// [1088..1599] pairBase[i]  (exclusive prefix sum of cnt)
// byte 8192+:  rel/att buffer, TRANSPOSED layout [c][strideP] floats

__global__ void k_groups(const int* __restrict__ imgid, int* __restrict__ wsI) {
    __shared__ int s_img[PP];
    __shared__ int s_cnt[PP];
    int t = threadIdx.x;
    s_img[t] = imgid[t];
    __syncthreads();
    int v = s_img[t];
    int lo = 0, hi = PP;
    while (lo < hi) { int mid = (lo + hi) >> 1; if (s_img[mid] < v) lo = mid + 1; else hi = mid; }
    int st = lo;
    lo = 0; hi = PP;
    while (lo < hi) { int mid = (lo + hi) >> 1; if (s_img[mid] <= v) lo = mid + 1; else hi = mid; }
    int cn = lo - st;
    wsI[64 + t]  = st;
    wsI[576 + t] = cn;
    s_cnt[t] = cn;
    if (t <= NIMG) {
        lo = 0; hi = PP;
        while (lo < hi) { int mid = (lo + hi) >> 1; if (s_img[mid] < t) lo = mid + 1; else hi = mid; }
        wsI[t] = lo;
    }
    __syncthreads();
    if (t == 0) {
        int acc = 0;
        for (int i = 0; i < PP; ++i) { wsI[1088 + i] = acc; acc += s_cnt[i]; }
        wsI[33] = acc;
    }
}

// rel[c][p(i,j)] = dot(x[c,i,:], x[c,j,:]) / 96   (transposed layout)
// MFMA version: one wave computes one 16x16 pair tile for one channel.
// A-frag and B-frag use the IDENTICAL (lane,e)->element load map, so the
// operand layout cancels; C/D uses the HW-verified mapping
// (col = lane&15, row = (lane>>4)*4 + reg). No LDS, 4 f32 accumulators.
// Grid: (image, channel/4, tile-slot z in [0,4)); block = 4 waves = 4 channels.
__global__ __launch_bounds__(256) void k_rel(const float* __restrict__ feats,
                                             const int* __restrict__ wsI,
                                             float* __restrict__ relbuf, int strideP) {
    int m = blockIdx.x, z = blockIdx.z;
    int g0 = wsI[m], n = wsI[m + 1] - g0;
    if (n <= 0) return;
    const int* pairBase = wsI + 1088;
    int t = threadIdx.x;
    int lane = t & 63, wave = t >> 6;
    int c = blockIdx.y * 4 + wave;
    int lr = lane & 15;            // row-within-tile for A/B loads, D col
    int kb = (lane >> 4) * 8;      // k-block base within each 32-chunk
    int nt = (n + 15) >> 4;        // 16-row tiles

    for (int tile = z; tile < nt * nt; tile += 4) {
        int ti = tile / nt, tj = tile - ti * nt;
        int i0 = 16 * ti, j0 = 16 * tj;
        int rA = i0 + lr; if (rA >= n) rA = n - 1;   // clamp; writes guarded
        int rB = j0 + lr; if (rB >= n) rB = n - 1;
        const float* pA = feats + ((size_t)(g0 + rA) * CC + c) * HWD + kb;
        const float* pB = feats + ((size_t)(g0 + rB) * CC + c) * HWD + kb;

        f32x4 acc = {0.f, 0.f, 0.f, 0.f};
#pragma unroll 2
        for (int k0 = 0; k0 < HWD; k0 += 32) {
            float4 a0 = *(const float4*)(pA + k0);
            float4 a1 = *(const float4*)(pA + k0 + 4);
            float4 b0 = *(const float4*)(pB + k0);
            float4 b1 = *(const float4*)(pB + k0 + 4);
            bf16x8 av, bv;
            av[0] = f2bf(a0.x); av[1] = f2bf(a0.y); av[2] = f2bf(a0.z); av[3] = f2bf(a0.w);
            av[4] = f2bf(a1.x); av[5] = f2bf(a1.y); av[6] = f2bf(a1.z); av[7] = f2bf(a1.w);
            bv[0] = f2bf(b0.x); bv[1] = f2bf(b0.y); bv[2] = f2bf(b0.z); bv[3] = f2bf(b0.w);
            bv[4] = f2bf(b1.x); bv[5] = f2bf(b1.y); bv[6] = f2bf(b1.z); bv[7] = f2bf(b1.w);
            acc = __builtin_amdgcn_mfma_f32_16x16x32_bf16(av, bv, acc, 0, 0, 0);
        }
#pragma unroll
        for (int q = 0; q < 4; ++q) {
            int i = i0 + (lane >> 4) * 4 + q;    // D row (A-side instance)
            int j = j0 + lr;                     // D col (B-side instance)
            if (i < n && j < n) {
                int p = pairBase[g0 + i] + j;
                if (p < strideP) relbuf[(size_t)c * strideP + p] = acc[q] * INV_NORM;
            }
        }
    }
}

// softmax over channels, tiled transpose for coalescing; adds param term
__global__ __launch_bounds__(256) void k_softmax(float* __restrict__ relbuf,
                                                 const float* __restrict__ param,
                                                 const int* __restrict__ wsI, int strideP) {
    int np = wsI[33];
    if (np > strideP) np = strideP;
    int p0 = blockIdx.x * 64;
    if (p0 >= np) return;
    int nv = min(64, np - p0);
    __shared__ float tile[CC][68];   // 8.7 KB
    int t = threadIdx.x;
    for (int idx = t; idx < CC * 16; idx += 256) {
        int c = idx >> 4, q4 = (idx & 15) * 4;
        if (q4 + 4 <= nv) {
            *(float4*)&tile[c][q4] = *(const float4*)&relbuf[(size_t)c * strideP + p0 + q4];
        } else {
#pragma unroll
            for (int e = 0; e < 4; ++e)
                if (q4 + e < nv) tile[c][q4 + e] = relbuf[(size_t)c * strideP + p0 + q4 + e];
        }
    }
    __syncthreads();
    if (t < 64 && t < nv) {
        int p = p0 + t;
        const int* pairBase = wsI + 1088;
        int lo = 0, hi = PP - 1;
        while (lo < hi) { int mid = (lo + hi + 1) >> 1; if (pairBase[mid] <= p) lo = mid; else hi = mid - 1; }
        int i = lo;
        int j = wsI[64 + i] + (p - pairBase[i]);
        float pd = 0.f;
#pragma unroll
        for (int k = 0; k < PDIMK; ++k) pd += param[i * PDIMK + k] * param[j * PDIMK + k];
        pd *= INV_PNORM;
        float mx = -3.4e38f;
#pragma unroll
        for (int c = 0; c < CC; ++c) mx = fmaxf(mx, tile[c][t] + pd);
        float s = 0.f;
#pragma unroll
        for (int c = 0; c < CC; ++c) { float e = __expf(tile[c][t] + pd - mx); tile[c][t] = e; s += e; }
        float inv = 1.0f / s;
#pragma unroll
        for (int c = 0; c < CC; ++c) tile[c][t] *= inv;
    }
    __syncthreads();
    for (int idx = t; idx < CC * 16; idx += 256) {
        int c = idx >> 4, q4 = (idx & 15) * 4;
        if (q4 + 4 <= nv) {
            *(float4*)&relbuf[(size_t)c * strideP + p0 + q4] = *(const float4*)&tile[c][q4];
        } else {
#pragma unroll
            for (int e = 0; e < 4; ++e)
                if (q4 + e < nv) relbuf[(size_t)c * strideP + p0 + q4 + e] = tile[c][q4 + e];
        }
    }
}

// out[i,c,d] = relu( sum_j (att[c,i,j] + delta_ij) * x[j,c,d] )
__global__ __launch_bounds__(256) void k_out(const float* __restrict__ feats,
                                             const float* __restrict__ att,
                                             const int* __restrict__ wsI,
                                             float* __restrict__ out, int strideP) {
    __shared__ float att_t[32][20];    // [jj][ii], 2.5 KB
    int m = blockIdx.x, c = blockIdx.y;
    int g0 = wsI[m], n = wsI[m + 1] - g0;
    if (n <= 0) return;
    const int* pairBase = wsI + 1088;
    int t = threadIdx.x;
    int col = blockIdx.z * 1024 + t * 4;
    const size_t rs = (size_t)CC * HWD;                     // row stride (floats)
    const float* fb = feats + ((size_t)g0 * CC + c) * HWD + col;
    float*       ob = out   + ((size_t)g0 * CC + c) * HWD + col;

    for (int ic = 0; ic < n; ic += 16) {
        int ni = min(16, n - ic);
        float4 acc[16];
#pragma unroll
        for (int q = 0; q < 16; ++q) acc[q] = make_float4(0.f, 0.f, 0.f, 0.f);
        for (int jc = 0; jc < n; jc += 32) {
            int nj = min(32, n - jc);
            __syncthreads();
            for (int idx = t; idx < 512; idx += 256) {      // 32 jj x 16 ii
                int jj = idx & 31, ii = idx >> 5;
                float a = 0.f;
                if (ii < ni && jj < nj) {
                    int p = pairBase[g0 + ic + ii] + jc + jj;
                    if (p < strideP) a = att[(size_t)c * strideP + p];
                    if (ic + ii == jc + jj) a += 1.0f;      // residual folded in
                }
                att_t[jj][ii] = a;
            }
            __syncthreads();
            const float* fj = fb + (size_t)jc * rs;
            float4 vnext = *(const float4*)fj;              // nj >= 1 always here
            for (int jj = 0; jj < nj; ++jj) {
                float4 vj = vnext;
                if (jj + 1 < nj) vnext = *(const float4*)(fj + (size_t)(jj + 1) * rs);
                float4 a0 = *(const float4*)&att_t[jj][0];   // broadcast reads
                float4 a1 = *(const float4*)&att_t[jj][4];
                float4 a2 = *(const float4*)&att_t[jj][8];
                float4 a3 = *(const float4*)&att_t[jj][12];
                acc[0].x  += a0.x * vj.x; acc[0].y  += a0.x * vj.y; acc[0].z  += a0.x * vj.z; acc[0].w  += a0.x * vj.w;
                acc[1].x  += a0.y * vj.x; acc[1].y  += a0.y * vj.y; acc[1].z  += a0.y * vj.z; acc[1].w  += a0.y * vj.w;
                acc[2].x  += a0.z * vj.x; acc[2].y  += a0.z * vj.y; acc[2].z  += a0.z * vj.z; acc[2].w  += a0.z * vj.w;
                acc[3].x  += a0.w * vj.x; acc[3].y  += a0.w * vj.y; acc[3].z  += a0.w * vj.z; acc[3].w  += a0.w * vj.w;
                acc[4].x  += a1.x * vj.x; acc[4].y  += a1.x * vj.y; acc[4].z  += a1.x * vj.z; acc[4].w  += a1.x * vj.w;
                acc[5].x  += a1.y * vj.x; acc[5].y  += a1.y * vj.y; acc[5].z  += a1.y * vj.z; acc[5].w  += a1.y * vj.w;
                acc[6].x  += a1.z * vj.x; acc[6].y  += a1.z * vj.y; acc[6].z  += a1.z * vj.z; acc[6].w  += a1.z * vj.w;
                acc[7].x  += a1.w * vj.x; acc[7].y  += a1.w * vj.y; acc[7].z  += a1.w * vj.z; acc[7].w  += a1.w * vj.w;
                acc[8].x  += a2.x * vj.x; acc[8].y  += a2.x * vj.y; acc[8].z  += a2.x * vj.z; acc[8].w  += a2.x * vj.w;
                acc[9].x  += a2.y * vj.x; acc[9].y  += a2.y * vj.y; acc[9].z  += a2.y * vj.z; acc[9].w  += a2.y * vj.w;
                acc[10].x += a2.z * vj.x; acc[10].y += a2.z * vj.y; acc[10].z += a2.z * vj.z; acc[10].w += a2.z * vj.w;
                acc[11].x += a2.w * vj.x; acc[11].y += a2.w * vj.y; acc[11].z += a2.w * vj.z; acc[11].w += a2.w * vj.w;
                acc[12].x += a3.x * vj.x; acc[12].y += a3.x * vj.y; acc[12].z += a3.x * vj.z; acc[12].w += a3.x * vj.w;
                acc[13].x += a3.y * vj.x; acc[13].y += a3.y * vj.y; acc[13].z += a3.y * vj.z; acc[13].w += a3.y * vj.w;
                acc[14].x += a3.z * vj.x; acc[14].y += a3.z * vj.y; acc[14].z += a3.z * vj.z; acc[14].w += a3.z * vj.w;
                acc[15].x += a3.w * vj.x; acc[15].y += a3.w * vj.y; acc[15].z += a3.w * vj.z; acc[15].w += a3.w * vj.w;
            }
        }
#pragma unroll
        for (int ii = 0; ii < 16; ++ii) {
            if (ii < ni) {
                float4 r = acc[ii];
                r.x = fmaxf(r.x, 0.f); r.y = fmaxf(r.y, 0.f);
                r.z = fmaxf(r.z, 0.f); r.w = fmaxf(r.w, 0.f);
                *(float4*)&ob[(size_t)(ic + ii) * rs] = r;
            }
        }
    }
}

extern "C" void kernel_launch(void* const* d_in, const int* in_sizes, int n_in,
                              void* d_out, int out_size, void* d_ws, size_t ws_size,
                              hipStream_t stream) {
    const float* feats = (const float*)d_in[0];
    const int*   imgid = (const int*)d_in[1];
    const float* param = (const float*)d_in[2];
    float* out = (float*)d_out;
    int* wsI = (int*)d_ws;
    float* relbuf = (float*)((char*)d_ws + 8192);

    long capL = ((long)ws_size - 8192) / (CC * 4);
    if (capL < 0) capL = 0;
    if (capL > (long)PP * PP) capL = (long)PP * PP;
    int strideP = (int)capL;

    k_groups<<<1, PP, 0, stream>>>(imgid, wsI);
    k_rel<<<dim3(NIMG, CC / 4, 4), 256, 0, stream>>>(feats, wsI, relbuf, strideP);
    k_softmax<<<dim3((PP * PP + 63) / 64), 256, 0, stream>>>(relbuf, param, wsI, strideP);
    k_out<<<dim3(NIMG, CC, 3), 256, 0, stream>>>(feats, relbuf, wsI, out, strideP);
}

// Round 8
// 236.990 us; speedup vs baseline: 3.9478x; 1.1064x over previous
//
#include <hip/hip_runtime.h>
#include <hip/hip_bf16.h>

#define PP   512
#define CC   32
#define HWD  3072           // 64*48
#define PDIMK 34
#define NIMG 32
#define KSL  (HWD / 4)      // 768 per K-slice

static constexpr float INV_NORM  = 1.0f / 96.0f;
static constexpr float INV_PNORM = 1.0f / 480.0f;

typedef short bf16x8 __attribute__((ext_vector_type(8)));
typedef float f32x4  __attribute__((ext_vector_type(4)));

__device__ __forceinline__ short f2bf(float f) {   // RNE fp32 -> bf16 bits
    __hip_bfloat16 h = __float2bfloat16(f);
    return *reinterpret_cast<short*>(&h);
}

// workspace int layout:
// [0..32]      gstart (33)
// [33]         npairs
// [64..575]    start[i]
// [576..1087]  cnt[i]
// [1088..1599] pairBase[i]  (exclusive prefix sum of cnt)
// byte 8192+:  rel/att buffer, TRANSPOSED layout [c][strideP] floats
// K-slice partials 1..3 live in d_out (fully overwritten by k_out later).

__global__ void k_groups(const int* __restrict__ imgid, int* __restrict__ wsI) {
    __shared__ int s_img[PP];
    __shared__ int s_cnt[PP];
    int t = threadIdx.x;
    s_img[t] = imgid[t];
    __syncthreads();
    int v = s_img[t];
    int lo = 0, hi = PP;
    while (lo < hi) { int mid = (lo + hi) >> 1; if (s_img[mid] < v) lo = mid + 1; else hi = mid; }
    int st = lo;
    lo = 0; hi = PP;
    while (lo < hi) { int mid = (lo + hi) >> 1; if (s_img[mid] <= v) lo = mid + 1; else hi = mid; }
    int cn = lo - st;
    wsI[64 + t]  = st;
    wsI[576 + t] = cn;
    s_cnt[t] = cn;
    if (t <= NIMG) {
        lo = 0; hi = PP;
        while (lo < hi) { int mid = (lo + hi) >> 1; if (s_img[mid] < t) lo = mid + 1; else hi = mid; }
        wsI[t] = lo;
    }
    __syncthreads();
    if (t == 0) {
        int acc = 0;
        for (int i = 0; i < PP; ++i) { wsI[1088 + i] = acc; acc += s_cnt[i]; }
        wsI[33] = acc;
    }
}

// rel[c][p(i,j)] = dot(x[c,i,:], x[c,j,:]) / 96, K-split into 4 partial sums.
// One wave = one 16x16 pair tile x one channel x one K-slice (24 MFMA iters).
// Grid: (image, channel/4, z = 4 tile-slots x 4 K-slices); block = 4 waves.
// A/B frags use identical (lane,e)->elem maps (layout cancels in X X^T);
// C/D mapping: col = lane&15, row = (lane>>4)*4 + reg (HW-verified).
// Diagonal tiles (ti==tj): A-rows == B-rows -> reuse converted frag.
__global__ __launch_bounds__(256) void k_rel(const float* __restrict__ feats,
                                             const int* __restrict__ wsI,
                                             float* __restrict__ relbuf,
                                             float* __restrict__ scratch,
                                             int strideP) {
    int m = blockIdx.x, z = blockIdx.z;
    int ks = z & 3, ts = z >> 2;
    int g0 = wsI[m], n = wsI[m + 1] - g0;
    if (n <= 0) return;
    const int* pairBase = wsI + 1088;
    int t = threadIdx.x;
    int lane = t & 63, wave = t >> 6;
    int c = blockIdx.y * 4 + wave;
    int lr = lane & 15;            // row-within-tile for A/B loads, D col
    int kb = (lane >> 4) * 8;      // k-block base within each 32-chunk
    int nt = (n + 15) >> 4;        // 16-row tiles
    int K0 = ks * KSL;
    float* dst = (ks == 0) ? relbuf : scratch + (size_t)(ks - 1) * CC * strideP;

    for (int tile = ts; tile < nt * nt; tile += 4) {
        int ti = tile / nt, tj = tile - ti * nt;
        bool diag = (ti == tj);
        int i0 = 16 * ti, j0 = 16 * tj;
        int rA = i0 + lr; if (rA >= n) rA = n - 1;   // clamp; writes guarded
        int rB = j0 + lr; if (rB >= n) rB = n - 1;
        const float* pA = feats + ((size_t)(g0 + rA) * CC + c) * HWD + K0 + kb;
        const float* pB = feats + ((size_t)(g0 + rB) * CC + c) * HWD + K0 + kb;

        f32x4 acc = {0.f, 0.f, 0.f, 0.f};
        if (diag) {
#pragma unroll 2
            for (int k0 = 0; k0 < KSL; k0 += 32) {
                float4 a0 = *(const float4*)(pA + k0);
                float4 a1 = *(const float4*)(pA + k0 + 4);
                bf16x8 av;
                av[0] = f2bf(a0.x); av[1] = f2bf(a0.y); av[2] = f2bf(a0.z); av[3] = f2bf(a0.w);
                av[4] = f2bf(a1.x); av[5] = f2bf(a1.y); av[6] = f2bf(a1.z); av[7] = f2bf(a1.w);
                acc = __builtin_amdgcn_mfma_f32_16x16x32_bf16(av, av, acc, 0, 0, 0);
            }
        } else {
#pragma unroll 2
            for (int k0 = 0; k0 < KSL; k0 += 32) {
                float4 a0 = *(const float4*)(pA + k0);
                float4 a1 = *(const float4*)(pA + k0 + 4);
                float4 b0 = *(const float4*)(pB + k0);
                float4 b1 = *(const float4*)(pB + k0 + 4);
                bf16x8 av, bv;
                av[0] = f2bf(a0.x); av[1] = f2bf(a0.y); av[2] = f2bf(a0.z); av[3] = f2bf(a0.w);
                av[4] = f2bf(a1.x); av[5] = f2bf(a1.y); av[6] = f2bf(a1.z); av[7] = f2bf(a1.w);
                bv[0] = f2bf(b0.x); bv[1] = f2bf(b0.y); bv[2] = f2bf(b0.z); bv[3] = f2bf(b0.w);
                bv[4] = f2bf(b1.x); bv[5] = f2bf(b1.y); bv[6] = f2bf(b1.z); bv[7] = f2bf(b1.w);
                acc = __builtin_amdgcn_mfma_f32_16x16x32_bf16(av, bv, acc, 0, 0, 0);
            }
        }
#pragma unroll
        for (int q = 0; q < 4; ++q) {
            int i = i0 + (lane >> 4) * 4 + q;    // D row (A-side instance)
            int j = j0 + lr;                     // D col (B-side instance)
            if (i < n && j < n) {
                int p = pairBase[g0 + i] + j;
                if (p < strideP) dst[(size_t)c * strideP + p] = acc[q] * INV_NORM;
            }
        }
    }
}

// softmax over channels: sum 4 K-slice partials + param term, tiled transpose
__global__ __launch_bounds__(256) void k_softmax(float* __restrict__ relbuf,
                                                 const float* __restrict__ scratch,
                                                 const float* __restrict__ param,
                                                 const int* __restrict__ wsI, int strideP) {
    int np = wsI[33];
    if (np > strideP) np = strideP;
    int p0 = blockIdx.x * 64;
    if (p0 >= np) return;
    int nv = min(64, np - p0);
    __shared__ float tile[CC][68];   // 8.7 KB
    int t = threadIdx.x;
    for (int idx = t; idx < CC * 16; idx += 256) {
        int c = idx >> 4, q4 = (idx & 15) * 4;
        size_t base = (size_t)c * strideP + p0 + q4;
        if (q4 + 4 <= nv) {
            float4 v = *(const float4*)&relbuf[base];
#pragma unroll
            for (int s = 0; s < 3; ++s) {
                float4 w = *(const float4*)&scratch[(size_t)s * CC * strideP + base];
                v.x += w.x; v.y += w.y; v.z += w.z; v.w += w.w;
            }
            *(float4*)&tile[c][q4] = v;
        } else {
#pragma unroll
            for (int e = 0; e < 4; ++e)
                if (q4 + e < nv) {
                    float v = relbuf[base + e];
#pragma unroll
                    for (int s = 0; s < 3; ++s)
                        v += scratch[(size_t)s * CC * strideP + base + e];
                    tile[c][q4 + e] = v;
                }
        }
    }
    __syncthreads();
    if (t < 64 && t < nv) {
        int p = p0 + t;
        const int* pairBase = wsI + 1088;
        int lo = 0, hi = PP - 1;
        while (lo < hi) { int mid = (lo + hi + 1) >> 1; if (pairBase[mid] <= p) lo = mid; else hi = mid - 1; }
        int i = lo;
        int j = wsI[64 + i] + (p - pairBase[i]);
        float pd = 0.f;
#pragma unroll
        for (int k = 0; k < PDIMK; ++k) pd += param[i * PDIMK + k] * param[j * PDIMK + k];
        pd *= INV_PNORM;
        float mx = -3.4e38f;
#pragma unroll
        for (int c = 0; c < CC; ++c) mx = fmaxf(mx, tile[c][t] + pd);
        float s = 0.f;
#pragma unroll
        for (int c = 0; c < CC; ++c) { float e = __expf(tile[c][t] + pd - mx); tile[c][t] = e; s += e; }
        float inv = 1.0f / s;
#pragma unroll
        for (int c = 0; c < CC; ++c) tile[c][t] *= inv;
    }
    __syncthreads();
    for (int idx = t; idx < CC * 16; idx += 256) {
        int c = idx >> 4, q4 = (idx & 15) * 4;
        if (q4 + 4 <= nv) {
            *(float4*)&relbuf[(size_t)c * strideP + p0 + q4] = *(const float4*)&tile[c][q4];
        } else {
#pragma unroll
            for (int e = 0; e < 4; ++e)
                if (q4 + e < nv) relbuf[(size_t)c * strideP + p0 + q4 + e] = tile[c][q4 + e];
        }
    }
}

// out[i,c,d] = relu( sum_j (att[c,i,j] + delta_ij) * x[j,c,d] )
__global__ __launch_bounds__(256) void k_out(const float* __restrict__ feats,
                                             const float* __restrict__ att,
                                             const int* __restrict__ wsI,
                                             float* __restrict__ out, int strideP) {
    __shared__ float att_t[32][20];    // [jj][ii], 2.5 KB
    int m = blockIdx.x, c = blockIdx.y;
    int g0 = wsI[m], n = wsI[m + 1] - g0;
    if (n <= 0) return;
    const int* pairBase = wsI + 1088;
    int t = threadIdx.x;
    int col = blockIdx.z * 1024 + t * 4;
    const size_t rs = (size_t)CC * HWD;                     // row stride (floats)
    const float* fb = feats + ((size_t)g0 * CC + c) * HWD + col;
    float*       ob = out   + ((size_t)g0 * CC + c) * HWD + col;

    for (int ic = 0; ic < n; ic += 16) {
        int ni = min(16, n - ic);
        float4 acc[16];
#pragma unroll
        for (int q = 0; q < 16; ++q) acc[q] = make_float4(0.f, 0.f, 0.f, 0.f);
        for (int jc = 0; jc < n; jc += 32) {
            int nj = min(32, n - jc);
            __syncthreads();
            for (int idx = t; idx < 512; idx += 256) {      // 32 jj x 16 ii
                int jj = idx & 31, ii = idx >> 5;
                float a = 0.f;
                if (ii < ni && jj < nj) {
                    int p = pairBase[g0 + ic + ii] + jc + jj;
                    if (p < strideP) a = att[(size_t)c * strideP + p];
                    if (ic + ii == jc + jj) a += 1.0f;      // residual folded in
                }
                att_t[jj][ii] = a;
            }
            __syncthreads();
            const float* fj = fb + (size_t)jc * rs;
            float4 vnext = *(const float4*)fj;              // nj >= 1 always here
            for (int jj = 0; jj < nj; ++jj) {
                float4 vj = vnext;
                if (jj + 1 < nj) vnext = *(const float4*)(fj + (size_t)(jj + 1) * rs);
                float4 a0 = *(const float4*)&att_t[jj][0];   // broadcast reads
                float4 a1 = *(const float4*)&att_t[jj][4];
                float4 a2 = *(const float4*)&att_t[jj][8];
                float4 a3 = *(const float4*)&att_t[jj][12];
                acc[0].x  += a0.x * vj.x; acc[0].y  += a0.x * vj.y; acc[0].z  += a0.x * vj.z; acc[0].w  += a0.x * vj.w;
                acc[1].x  += a0.y * vj.x; acc[1].y  += a0.y * vj.y; acc[1].z  += a0.y * vj.z; acc[1].w  += a0.y * vj.w;
                acc[2].x  += a0.z * vj.x; acc[2].y  += a0.z * vj.y; acc[2].z  += a0.z * vj.z; acc[2].w  += a0.z * vj.w;
                acc[3].x  += a0.w * vj.x; acc[3].y  += a0.w * vj.y; acc[3].z  += a0.w * vj.z; acc[3].w  += a0.w * vj.w;
                acc[4].x  += a1.x * vj.x; acc[4].y  += a1.x * vj.y; acc[4].z  += a1.x * vj.z; acc[4].w  += a1.x * vj.w;
                acc[5].x  += a1.y * vj.x; acc[5].y  += a1.y * vj.y; acc[5].z  += a1.y * vj.z; acc[5].w  += a1.y * vj.w;
                acc[6].x  += a1.z * vj.x; acc[6].y  += a1.z * vj.y; acc[6].z  += a1.z * vj.z; acc[6].w  += a1.z * vj.w;
                acc[7].x  += a1.w * vj.x; acc[7].y  += a1.w * vj.y; acc[7].z  += a1.w * vj.z; acc[7].w  += a1.w * vj.w;
                acc[8].x  += a2.x * vj.x; acc[8].y  += a2.x * vj.y; acc[8].z  += a2.x * vj.z; acc[8].w  += a2.x * vj.w;
                acc[9].x  += a2.y * vj.x; acc[9].y  += a2.y * vj.y; acc[9].z  += a2.y * vj.z; acc[9].w  += a2.y * vj.w;
                acc[10].x += a2.z * vj.x; acc[10].y += a2.z * vj.y; acc[10].z += a2.z * vj.z; acc[10].w += a2.z * vj.w;
                acc[11].x += a2.w * vj.x; acc[11].y += a2.w * vj.y; acc[11].z += a2.w * vj.z; acc[11].w += a2.w * vj.w;
                acc[12].x += a3.x * vj.x; acc[12].y += a3.x * vj.y; acc[12].z += a3.x * vj.z; acc[12].w += a3.x * vj.w;
                acc[13].x += a3.y * vj.x; acc[13].y += a3.y * vj.y; acc[13].z += a3.y * vj.z; acc[13].w += a3.y * vj.w;
                acc[14].x += a3.z * vj.x; acc[14].y += a3.z * vj.y; acc[14].z += a3.z * vj.z; acc[14].w += a3.z * vj.w;
                acc[15].x += a3.w * vj.x; acc[15].y += a3.w * vj.y; acc[15].z += a3.w * vj.z; acc[15].w += a3.w * vj.w;
            }
        }
#pragma unroll
        for (int ii = 0; ii < 16; ++ii) {
            if (ii < ni) {
                float4 r = acc[ii];
                r.x = fmaxf(r.x, 0.f); r.y = fmaxf(r.y, 0.f);
                r.z = fmaxf(r.z, 0.f); r.w = fmaxf(r.w, 0.f);
                *(float4*)&ob[(size_t)(ic + ii) * rs] = r;
            }
        }
    }
}

extern "C" void kernel_launch(void* const* d_in, const int* in_sizes, int n_in,
                              void* d_out, int out_size, void* d_ws, size_t ws_size,
                              hipStream_t stream) {
    const float* feats = (const float*)d_in[0];
    const int*   imgid = (const int*)d_in[1];
    const float* param = (const float*)d_in[2];
    float* out = (float*)d_out;
    int* wsI = (int*)d_ws;
    float* relbuf = (float*)((char*)d_ws + 8192);
    float* scratch = out;   // K-slice partials 1..3; fully overwritten by k_out

    long capL = ((long)ws_size - 8192) / (CC * 4);
    if (capL < 0) capL = 0;
    if (capL > (long)PP * PP) capL = (long)PP * PP;
    int strideP = (int)capL;

    k_groups<<<1, PP, 0, stream>>>(imgid, wsI);
    k_rel<<<dim3(NIMG, CC / 4, 16), 256, 0, stream>>>(feats, wsI, relbuf, scratch, strideP);
    k_softmax<<<dim3((PP * PP + 63) / 64), 256, 0, stream>>>(relbuf, scratch, param, wsI, strideP);
    k_out<<<dim3(NIMG, CC, 3), 256, 0, stream>>>(feats, relbuf, wsI, out, strideP);
}